// Round 1
// 305.036 us; speedup vs baseline: 1.2730x; 1.2730x over previous
//
#include <hip/hip_runtime.h>
#include <hip/hip_bf16.h>

// LexionAdapter — fp32 I/O, bf16-MFMA compute.
//   prep_wt : Wt  -> fragment-ordered bf16 image (344 KB, L2-resident)
//   prep_ww : Ww  -> fragment-ordered bf16 image (1.18 MB, L2-resident)
//   Wc = attn_W . Ww                      (NN gemm)  -> ws
//   R  = LO . Wc                          (NN gemm)  -> d_out
//   x1_attn : fused X1 = tanh(WE.Wt^T+bt) + logits + softmax + Y.
//             64 rows/block, X1 kept in REGISTERS (bf16), B-fragments read
//             directly from global (L2) -> ZERO barriers in the K loop.
//             X1 never hits HBM. Writes Y as bf16 (Yb in ws).
//   y_ww_ln : out = LN(Y.Ww^T + bw + LO). A-frags from Yb, B-frags from Ww
//             image, ping-pong prefetch, no LDS staging, no K-loop barriers.
// q.bw logit term is w-constant -> cancels in softmax; sum(alpha)=1.

typedef __bf16 bf16_t;
typedef bf16_t bf16x4 __attribute__((ext_vector_type(4)));
typedef bf16_t bf16x8 __attribute__((ext_vector_type(8)));
typedef float f32x4 __attribute__((ext_vector_type(4)));

__device__ __forceinline__ bf16x4 cvt4(float4 v) {
  bf16x4 o;
  o[0] = (bf16_t)v.x; o[1] = (bf16_t)v.y;
  o[2] = (bf16_t)v.z; o[3] = (bf16_t)v.w;
  return o;
}

// ---------------------------------------------------------------------------
// Wt [768,200] fp32 -> Wtb fragment image: [nt=6][jg=8][kt=7][lane=64][8]
// fragment: lane (quad,l16) holds B[n = nt*128+jg*16+l16][k = kt*32+quad*8 ..+8]
// k >= 200 zero-padded (K padded to 224).
// ---------------------------------------------------------------------------
__global__ void prep_wt(const float* __restrict__ Wt, bf16_t* __restrict__ Wtb) {
  const int u = blockIdx.x * 256 + threadIdx.x;  // 21504 chunks of 8
  const int lane = u & 63;
  const int v = u >> 6;        // 336 = 6*8*7
  const int kt = v % 7;
  const int v2 = v / 7;        // 48 = 6*8
  const int jg = v2 & 7, nt = v2 >> 3;
  const int l16 = lane & 15, quad = lane >> 4;
  const int n = nt * 128 + jg * 16 + l16;
  const int k0 = kt * 32 + quad * 8;
  float4 a = {0.f, 0.f, 0.f, 0.f}, b = {0.f, 0.f, 0.f, 0.f};
  if (k0 < 200) {
    a = *(const float4*)(Wt + n * 200 + k0);
    b = *(const float4*)(Wt + n * 200 + k0 + 4);
  }
  *(bf16x4*)&Wtb[u * 8] = cvt4(a);
  *(bf16x4*)&Wtb[u * 8 + 4] = cvt4(b);
}

// ---------------------------------------------------------------------------
// Ww [768,768] fp32 -> Wwf fragment image: [jg=48][kt=24][lane=64][8]
// fragment: lane (quad,l16) holds Ww[n = jg*16+l16][k = kt*32+quad*8 ..+8]
// ---------------------------------------------------------------------------
__global__ void prep_ww(const float* __restrict__ Ww, bf16_t* __restrict__ Wwf) {
  const int u = blockIdx.x * 256 + threadIdx.x;  // 73728 chunks of 8
  const int lane = u & 63;
  const int v = u >> 6;        // 1152 = 48*24
  const int kt = v % 24;
  const int jg = v / 24;
  const int l16 = lane & 15, quad = lane >> 4;
  const long n = jg * 16 + l16;
  const int k0 = kt * 32 + quad * 8;
  float4 a = *(const float4*)(Ww + n * 768 + k0);
  float4 b = *(const float4*)(Ww + n * 768 + k0 + 4);
  *(bf16x4*)&Wwf[u * 8] = cvt4(a);
  *(bf16x4*)&Wwf[u * 8 + 4] = cvt4(b);
}

// ---------------------------------------------------------------------------
// NN GEMM: C[M,N] = A[M,K].B[K,N], fp32, K = 32*kFull. 128x128 tile.
// (Wc and R — unchanged.)
// ---------------------------------------------------------------------------
__global__ __launch_bounds__(256, 2) void gemm_nn(
    const float* __restrict__ A, const float* __restrict__ B,
    float* __restrict__ C, int ldA, int ldB, int N_out, int kFull) {
  __shared__ __align__(16) bf16_t As[128 * 32];  // [m][k]
  __shared__ __align__(16) bf16_t Bs[32 * 128];  // [k][n]

  const int t = threadIdx.x;
  const int lane = t & 63, wave = t >> 6;
  const int wr = wave >> 1, wc = wave & 1;
  const int quad = lane >> 4, l16 = lane & 15;
  const long m0 = (long)blockIdx.y * 128;
  const long n0 = (long)blockIdx.x * 128;

  f32x4 acc[4][4] = {};

  for (int kt = 0; kt < kFull; ++kt) {
    const int k0 = kt * 32;
#pragma unroll
    for (int r = 0; r < 4; ++r) {
      const int f = r * 256 + t;
      const int arow = f >> 3, ak = (f & 7) * 4;
      float4 va = *(const float4*)(A + (m0 + arow) * ldA + k0 + ak);
      *(bf16x4*)&As[arow * 32 + ak] = cvt4(va);
      const int brow = f >> 5, bc = (f & 31) * 4;
      float4 vb = *(const float4*)(B + (long)(k0 + brow) * ldB + n0 + bc);
      *(bf16x4*)&Bs[brow * 128 + bc] = cvt4(vb);
    }
    __syncthreads();

    bf16x8 af[4], bfv[4];
#pragma unroll
    for (int i = 0; i < 4; ++i)
      af[i] = *(const bf16x8*)&As[(wr * 64 + i * 16 + l16) * 32 + quad * 8];
#pragma unroll
    for (int j = 0; j < 4; ++j) {
      const int n = wc * 64 + j * 16 + l16;
#pragma unroll
      for (int jj = 0; jj < 8; ++jj)
        bfv[j][jj] = Bs[(quad * 8 + jj) * 128 + n];
    }
#pragma unroll
    for (int i = 0; i < 4; ++i)
#pragma unroll
      for (int j = 0; j < 4; ++j)
        acc[i][j] = __builtin_amdgcn_mfma_f32_16x16x32_bf16(af[i], bfv[j],
                                                            acc[i][j], 0, 0, 0);
    __syncthreads();
  }

#pragma unroll
  for (int j = 0; j < 4; ++j) {
    const long n = n0 + wc * 64 + j * 16 + l16;
#pragma unroll
    for (int i = 0; i < 4; ++i) {
      const long mBase = m0 + wr * 64 + i * 16 + quad * 4;
#pragma unroll
      for (int r = 0; r < 4; ++r)
        C[(mBase + r) * N_out + n] = acc[i][j][r];
    }
  }
}

// ---------------------------------------------------------------------------
// Fused X1 + attention. One block = 64 WE rows (8 word-groups) x all 768 cols.
//   - WE tile staged once to LDS (bf16, padded stride 232 -> 2-way banks).
//   - B-fragments loaded straight from Wtb (global/L2): no barriers in K loop.
//   - X1 stays in registers (bf16x4 st[6][2][4] = 96 VGPRs).
//   - logits vs R accumulated in epilogue; cross-lane reduce; softmax; Y->bf16.
// ---------------------------------------------------------------------------
#define ASF_LD 232
__global__ __launch_bounds__(256, 2) void x1_attn(
    const float* __restrict__ WE, const bf16_t* __restrict__ Wtb,
    const float* __restrict__ bt, const float* __restrict__ R,
    bf16_t* __restrict__ Yb) {
  __shared__ __align__(16) bf16_t As[64 * ASF_LD];  // 29 KiB
  __shared__ float red[8][8][2];
  __shared__ float alphaS[8][8];

  const int t = threadIdx.x;
  const int lane = t & 63, wave = t >> 6;
  const int wr = wave >> 1, wc = wave & 1;
  const int quad = lane >> 4, l16 = lane & 15;
  const int ghalf = quad >> 1, wq = (quad & 1) * 4;
  const long m0 = (long)blockIdx.x * 64;
  const long gbase = (long)blockIdx.x * 8;

  // ---- stage WE tile (64 x 200 fp32 -> bf16), zero-pad k 200..231 ----
  const float* WEb = WE + m0 * 200;
#pragma unroll
  for (int r = 0; r < 13; ++r) {
    const int f = r * 256 + t;  // 3200 float4 total
    if (f < 3200) {
      const int row = f / 50, idx = f - row * 50;
      *(bf16x4*)&As[row * ASF_LD + idx * 4] =
          cvt4(*(const float4*)(WEb + 4 * f));
    }
  }
  {
    const bf16x4 z4 = {(bf16_t)0.f, (bf16_t)0.f, (bf16_t)0.f, (bf16_t)0.f};
#pragma unroll
    for (int p = 0; p < 2; ++p) {
      const int s = p * 256 + t;  // 512 slots
      *(bf16x4*)&As[(s >> 3) * ASF_LD + 200 + (s & 7) * 4] = z4;
    }
  }
  __syncthreads();  // the ONLY barrier before the reductions

  bf16x4 st[6][2][4];        // X1 stash (bf16), fully unrolled indexing
  float pl[2][4] = {};       // logit partials

#pragma unroll
  for (int nt = 0; nt < 6; ++nt) {
    f32x4 acc[2][4] = {};
    const bf16_t* bb = Wtb + ((nt * 8 + wc * 4) * 7) * 512 + lane * 8;
#pragma unroll
    for (int kt = 0; kt < 7; ++kt) {
      bf16x8 af[2], bf[4];
#pragma unroll
      for (int i = 0; i < 2; ++i)
        af[i] = *(const bf16x8*)&As[(wr * 32 + i * 16 + l16) * ASF_LD +
                                    kt * 32 + quad * 8];
#pragma unroll
      for (int j = 0; j < 4; ++j)
        bf[j] = *(const bf16x8*)&bb[(j * 7 + kt) * 512];
#pragma unroll
      for (int i = 0; i < 2; ++i)
#pragma unroll
        for (int j = 0; j < 4; ++j)
          acc[i][j] = __builtin_amdgcn_mfma_f32_16x16x32_bf16(
              af[i], bf[j], acc[i][j], 0, 0, 0);
    }
    // epilogue: tanh, stash, logit partials. C/D: col=l16, row=quad*4+r.
    const int nb = nt * 128 + wc * 64;
#pragma unroll
    for (int j = 0; j < 4; ++j) {
      const int n = nb + j * 16 + l16;
      const float btv = bt[n];
#pragma unroll
      for (int i = 0; i < 2; ++i) {
        const long grow = gbase + 4 * wr + 2 * i + ghalf;
        const float Rv = R[grow * 768 + n];
#pragma unroll
        for (int r = 0; r < 4; ++r) {
          const float vv = acc[i][j][r] + btv;
          const float e = __expf(2.f * vv);            // tanh = 1 - 2/(e^2x+1)
          const float x = 1.f - __fdividef(2.f, e + 1.f);
          st[nt][i][j][r] = (bf16_t)x;
          pl[i][r] += x * Rv;
        }
      }
    }
  }

  // ---- logit reduce over the 16 column-lanes ----
#pragma unroll
  for (int o = 8; o > 0; o >>= 1)
#pragma unroll
    for (int i = 0; i < 2; ++i)
#pragma unroll
      for (int r = 0; r < 4; ++r)
        pl[i][r] += __shfl_down(pl[i][r], o, 16);
  if (l16 == 0) {
#pragma unroll
    for (int i = 0; i < 2; ++i)
#pragma unroll
      for (int r = 0; r < 4; ++r)
        red[4 * wr + 2 * i + ghalf][wq + r][wc] = pl[i][r];
  }
  __syncthreads();

  // ---- softmax (wave 0: one lane per (g,w)) ----
  if (t < 64) {
    const int g = t >> 3, w = t & 7;
    const float lg = red[g][w][0] + red[g][w][1];
    float mx = lg;
#pragma unroll
    for (int o = 4; o > 0; o >>= 1) mx = fmaxf(mx, __shfl_xor(mx, o, 8));
    const float e = __expf(lg - mx);
    float s = e;
#pragma unroll
    for (int o = 4; o > 0; o >>= 1) s += __shfl_xor(s, o, 8);
    alphaS[g][w] = __fdividef(e, s);
  }
  __syncthreads();

  // ---- Y = sum_w alpha[w] * X1[w]  (pair quads q and q^1 hold w 0-3 / 4-7) --
#pragma unroll
  for (int i = 0; i < 2; ++i) {
    const int glo = 4 * wr + 2 * i + ghalf;
    const long grow = gbase + glo;
    const float a0 = alphaS[glo][wq + 0], a1 = alphaS[glo][wq + 1];
    const float a2 = alphaS[glo][wq + 2], a3 = alphaS[glo][wq + 3];
#pragma unroll
    for (int nt = 0; nt < 6; ++nt) {
#pragma unroll
      for (int j = 0; j < 4; ++j) {
        float py = a0 * (float)st[nt][i][j][0] + a1 * (float)st[nt][i][j][1] +
                   a2 * (float)st[nt][i][j][2] + a3 * (float)st[nt][i][j][3];
        py += __shfl_xor(py, 16);
        if ((quad & 1) == 0)
          Yb[grow * 768 + nt * 128 + wc * 64 + j * 16 + l16] = (bf16_t)py;
      }
    }
  }
}

// ---------------------------------------------------------------------------
// out = LN(Y.Ww^T + bw + LO). One block = 32 rows x all 768 cols.
// A-frags direct from Yb (bf16), B-frags direct from Wwf image (L2).
// Ping-pong prefetch; no LDS staging; no barriers until row-stat exchange.
// ---------------------------------------------------------------------------
__global__ __launch_bounds__(256, 2) void y_ww_ln(
    const bf16_t* __restrict__ Yb, const bf16_t* __restrict__ Wwf,
    const float* __restrict__ bw, const float* __restrict__ LO,
    const float* __restrict__ gamma, const float* __restrict__ beta,
    float* __restrict__ out) {
  __shared__ float rowstats[32][4][2];

  const int t = threadIdx.x;
  const int lane = t & 63, wc = t >> 6;  // wave wc owns n-slab wc*192
  const int quad = lane >> 4, l16 = lane & 15;
  const long m0 = (long)blockIdx.x * 32;

  f32x4 acc[2][12] = {};

#define LD_FRAGS(af_, bf_, kt_)                                               \
  {                                                                           \
    _Pragma("unroll") for (int i_ = 0; i_ < 2; ++i_)                          \
        af_[i_] = *(const bf16x8*)&Yb[(m0 + i_ * 16 + l16) * 768 +            \
                                      (kt_) * 32 + quad * 8];                 \
    _Pragma("unroll") for (int j_ = 0; j_ < 12; ++j_)                         \
        bf_[j_] = *(const bf16x8*)&Wwf[(((wc * 12 + j_) * 24 + (kt_)) << 9) + \
                                       lane * 8];                             \
  }

  bf16x8 afA[2], bfA[12], afB[2], bfB[12];
  LD_FRAGS(afA, bfA, 0);
  for (int kt = 0; kt < 24; kt += 2) {
    LD_FRAGS(afB, bfB, kt + 1);
#pragma unroll
    for (int i = 0; i < 2; ++i)
#pragma unroll
      for (int j = 0; j < 12; ++j)
        acc[i][j] = __builtin_amdgcn_mfma_f32_16x16x32_bf16(afA[i], bfA[j],
                                                            acc[i][j], 0, 0, 0);
    if (kt + 2 < 24) LD_FRAGS(afA, bfA, kt + 2);
#pragma unroll
    for (int i = 0; i < 2; ++i)
#pragma unroll
      for (int j = 0; j < 12; ++j)
        acc[i][j] = __builtin_amdgcn_mfma_f32_16x16x32_bf16(afB[i], bfB[j],
                                                            acc[i][j], 0, 0, 0);
  }
#undef LD_FRAGS

  // epilogue: fv = acc + bw + LO; row stats; LN; store fp32.
  float s1[2][4] = {}, s2[2][4] = {};
#pragma unroll
  for (int i = 0; i < 2; ++i)
#pragma unroll
    for (int j = 0; j < 12; ++j) {
      const int n = wc * 192 + j * 16 + l16;
      const float bwv = bw[n];
#pragma unroll
      for (int r = 0; r < 4; ++r) {
        const int ml = i * 16 + quad * 4 + r;
        const float fv = acc[i][j][r] + bwv + LO[(m0 + ml) * 768 + n];
        acc[i][j][r] = fv;
        s1[i][r] += fv;
        s2[i][r] += fv * fv;
      }
    }
#pragma unroll
  for (int o = 8; o > 0; o >>= 1)
#pragma unroll
    for (int i = 0; i < 2; ++i)
#pragma unroll
      for (int r = 0; r < 4; ++r) {
        s1[i][r] += __shfl_down(s1[i][r], o, 16);
        s2[i][r] += __shfl_down(s2[i][r], o, 16);
      }
  if (l16 == 0)
#pragma unroll
    for (int i = 0; i < 2; ++i)
#pragma unroll
      for (int r = 0; r < 4; ++r) {
        const int ml = i * 16 + quad * 4 + r;
        rowstats[ml][wc][0] = s1[i][r];
        rowstats[ml][wc][1] = s2[i][r];
      }
  __syncthreads();

#pragma unroll
  for (int i = 0; i < 2; ++i) {
    float mu[4], istd[4];
#pragma unroll
    for (int r = 0; r < 4; ++r) {
      const int ml = i * 16 + quad * 4 + r;
      const float S1 = rowstats[ml][0][0] + rowstats[ml][1][0] +
                       rowstats[ml][2][0] + rowstats[ml][3][0];
      const float S2 = rowstats[ml][0][1] + rowstats[ml][1][1] +
                       rowstats[ml][2][1] + rowstats[ml][3][1];
      mu[r] = S1 * (1.f / 768.f);
      const float var = S2 * (1.f / 768.f) - mu[r] * mu[r];
      istd[r] = rsqrtf(var + 1e-12f);
    }
#pragma unroll
    for (int j = 0; j < 12; ++j) {
      const int n = wc * 192 + j * 16 + l16;
      const float gv = gamma[n], bv = beta[n];
#pragma unroll
      for (int r = 0; r < 4; ++r) {
        const int ml = i * 16 + quad * 4 + r;
        out[(m0 + ml) * 768 + n] = (acc[i][j][r] - mu[r]) * istd[r] * gv + bv;
      }
    }
  }
}

// ---------------------------------------------------------------------------
extern "C" void kernel_launch(void* const* d_in, const int* in_sizes, int n_in,
                              void* d_out, int out_size, void* d_ws,
                              size_t ws_size, hipStream_t stream) {
  (void)in_sizes; (void)n_in; (void)out_size; (void)ws_size;
  const float* WE = (const float*)d_in[0];   // [65536, 200]
  const float* LO = (const float*)d_in[1];   // [8192, 768]
  const float* Wt = (const float*)d_in[2];   // [768, 200]
  const float* bt = (const float*)d_in[3];   // [768]
  const float* Ww = (const float*)d_in[4];   // [768, 768]
  const float* bw = (const float*)d_in[5];   // [768]
  const float* aW = (const float*)d_in[6];   // [768, 768]
  const float* g  = (const float*)d_in[7];   // [768]
  const float* bb = (const float*)d_in[8];   // [768]
  float* out = (float*)d_out;                // [8192, 768]

  char* ws = (char*)d_ws;
  const size_t WC_BYTES  = (size_t)768 * 768 * 4;        // 2359296
  const size_t WTB_BYTES = (size_t)6 * 8 * 7 * 64 * 8 * 2;   // 344064
  const size_t WWF_BYTES = (size_t)48 * 24 * 64 * 8 * 2;     // 1179648
  float*  Wc  = (float*)ws;
  bf16_t* Wtb = (bf16_t*)(ws + WC_BYTES);
  bf16_t* Wwf = (bf16_t*)(ws + WC_BYTES + WTB_BYTES);
  bf16_t* Yb  = (bf16_t*)(ws + WC_BYTES + WTB_BYTES + WWF_BYTES);  // 12.6 MB

  const dim3 blk(256);

  prep_wt<<<dim3(84), blk, 0, stream>>>(Wt, Wtb);
  prep_ww<<<dim3(288), blk, 0, stream>>>(Ww, Wwf);
  // Wc = attn_W . Ww
  gemm_nn<<<dim3(6, 6), blk, 0, stream>>>(aW, Ww, Wc, 768, 768, 768, 24);
  // R = LO . Wc -> d_out
  gemm_nn<<<dim3(6, 64), blk, 0, stream>>>(LO, Wc, out, 768, 768, 768, 24);
  // fused X1 + attention -> Yb (bf16)
  x1_attn<<<dim3(1024), blk, 0, stream>>>(WE, Wtb, bt, out, Yb);
  // final GEMM + residual + LN -> out
  y_ww_ln<<<dim3(256), blk, 0, stream>>>(Yb, Wwf, bw, LO, g, bb, out);
}